// Round 1
// baseline (307.481 us; speedup 1.0000x reference)
//
#include <hip/hip_runtime.h>
#include <stdint.h>

typedef unsigned short u16;
typedef short s16x8 __attribute__((ext_vector_type(8)));
typedef float f32x4 __attribute__((ext_vector_type(4)));

__device__ __forceinline__ u16 f2bf(float f) {
  union { float f; uint32_t u; } a; a.f = f;
  uint32_t u = a.u;
  uint32_t r = (u + 0x7fffu + ((u >> 16) & 1u)) >> 16;
  return (u16)r;
}
__device__ __forceinline__ float bf2f(uint32_t hbits) {
  union { uint32_t u; float f; } a; a.u = hbits << 16;
  return a.f;
}

// ---------------------------------------------------------------- W -> bf16
__global__ void convert_w_kernel(const float* __restrict__ ws_w,
                                 const float* __restrict__ wp_w,
                                 u16* __restrict__ dst_ws, u16* __restrict__ dst_wp) {
  int i = blockIdx.x * 256 + threadIdx.x;
  if (i < 153600) dst_ws[i] = f2bf(ws_w[i]);
  if (i < 6144)   dst_wp[i] = f2bf(wp_w[i]);
}

// --------------------------------------------- [B,192,HW] f32 -> [B,HW,192] bf16
__global__ __launch_bounds__(256) void transpose_kernel(const float* __restrict__ src,
                                                        u16* __restrict__ dst, int HW) {
  __shared__ u16 tile[192][66];   // row stride 66 ushorts = 33 dwords (odd) -> 2-way max
  const int b = blockIdx.y;
  const int hw0 = blockIdx.x * 64;
  const int t = threadIdx.x;
  const float* s = src + (size_t)b * 192 * HW + hw0;
  for (int i = 0; i < 48; ++i) {
    int idx = i * 256 + t;
    int c = idx >> 6, hw = idx & 63;           // consecutive t -> consecutive hw (coalesced)
    tile[c][hw] = f2bf(s[(size_t)c * HW + hw]);
  }
  __syncthreads();
  uint32_t* d = (uint32_t*)(dst + ((size_t)b * HW + hw0) * 192);
  for (int i = 0; i < 24; ++i) {
    int e = i * 256 + t;
    int hw = e / 96, c2 = e - hw * 96;         // consecutive t -> consecutive c2 (coalesced)
    uint32_t v = (uint32_t)tile[c2 * 2][hw] | ((uint32_t)tile[c2 * 2 + 1][hw] << 16);
    d[hw * 96 + c2] = v;
  }
}

// ---------------------------------------------------------------- main fused
// 32 points per block, 256 threads (4 waves). x-tile [32][808] bf16 in LDS,
// MFMA 16x16x32 bf16: seed (K=800) + pos (K=32 reusing PE chunk). LN fused.
__global__ __launch_bounds__(256, 2) void seed_main(
    const float* __restrict__ coords,
    const u16* __restrict__ T1, const u16* __restrict__ T2,
    const u16* __restrict__ T3, const u16* __restrict__ T4,
    const u16* __restrict__ Wseed, const u16* __restrict__ Wpos,
    const float* __restrict__ seed_b, const float* __restrict__ ln_g,
    const float* __restrict__ ln_b, const float* __restrict__ pos_b,
    float* __restrict__ out_seed, float* __restrict__ out_pos,
    float* __restrict__ out_cg) {

  __shared__ __align__(16) u16 xt[32 * 808];   // 51.7 KB; later aliased as preLN f32 [32][193]
  __shared__ int   coff[32][4][4];
  __shared__ float cw[32][4][4];
  __shared__ float mu_s[32], rs_s[32];

  const int t = threadIdx.x;
  const int gp0 = blockIdx.x * 32;             // global point base (4096 pts/batch, 128 blocks/batch)
  const int b = gp0 >> 12;

  // ---- phase 0: per (point, level) corner offsets + weights; center_grid out
  if (t < 128) {
    int p = t >> 2, lv = t & 3;
    float cx = coords[(gp0 + p) * 2 + 0];
    float cy = coords[(gp0 + p) * 2 + 1];
    float gx = 2.0f * cx / 511.0f - 1.0f;
    float gy = 2.0f * cy / 511.0f - 1.0f;
    if (lv == 0) {
      out_cg[(gp0 + p) * 2 + 0] = gx;
      out_cg[(gp0 + p) * 2 + 1] = gy;
    }
    int Wl = 128 >> lv;
    float ix = (gx + 1.0f) * 0.5f * (float)(Wl - 1);
    float iy = (gy + 1.0f) * 0.5f * (float)(Wl - 1);
    float fx = floorf(ix), fy = floorf(iy);
    float wx = ix - fx, wy = iy - fy;
    int x0 = (int)fx, y0 = (int)fy;
    int x1 = x0 + 1, y1 = y0 + 1;
    x0 = min(max(x0, 0), Wl - 1); x1 = min(max(x1, 0), Wl - 1);
    y0 = min(max(y0, 0), Wl - 1); y1 = min(max(y1, 0), Wl - 1);
    coff[p][lv][0] = (y0 * Wl + x0) * 192;
    coff[p][lv][1] = (y0 * Wl + x1) * 192;
    coff[p][lv][2] = (y1 * Wl + x0) * 192;
    coff[p][lv][3] = (y1 * Wl + x1) * 192;
    cw[p][lv][0] = (1.0f - wx) * (1.0f - wy);
    cw[p][lv][1] = wx * (1.0f - wy);
    cw[p][lv][2] = (1.0f - wx) * wy;
    cw[p][lv][3] = wx * wy;
  }
  // ---- PE: 32 pts x 32 vals; order [sin x*f, cos x*f, sin y*f, cos y*f], f=2^(j&7)
  for (int i = 0; i < 4; ++i) {
    int e = i * 256 + t;
    int p = e >> 5, j = e & 31;
    float c = coords[(gp0 + p) * 2 + ((j >> 4) & 1)] * (1.0f / 512.0f);
    float v = c * (float)(1 << (j & 7));
    float a = (v - floorf(v)) * 6.283185307179586f;  // sin(2*pi*v) == sin(2*pi*frac(v))
    float r = (j & 8) ? cosf(a) : sinf(a);
    xt[p * 808 + 768 + j] = f2bf(r);
  }
  __syncthreads();

  // ---- gather: fill x[32][768] bf16 from transposed features (2 channels/thread)
  const size_t psz1 = (size_t)16384 * 192, psz2 = (size_t)4096 * 192,
               psz3 = (size_t)1024 * 192,  psz4 = (size_t)256 * 192;
  const u16* B1 = T1 + (size_t)b * psz1;
  const u16* B2 = T2 + (size_t)b * psz2;
  const u16* B3 = T3 + (size_t)b * psz3;
  const u16* B4 = T4 + (size_t)b * psz4;
  for (int i = 0; i < 48; ++i) {
    int e = i * 256 + t;                 // e = (p*4+lv)*96 + c2 ; consecutive t -> consecutive c2
    int c2 = e % 96;
    int plv = e / 96;
    int lv = plv & 3, p = plv >> 2;
    const u16* base = (lv == 0) ? B1 : (lv == 1) ? B2 : (lv == 2) ? B3 : B4;
    float w0 = cw[p][lv][0], w1 = cw[p][lv][1], w2 = cw[p][lv][2], w3 = cw[p][lv][3];
    int cc = c2 * 2;
    uint32_t u0 = *(const uint32_t*)(base + coff[p][lv][0] + cc);
    uint32_t u1 = *(const uint32_t*)(base + coff[p][lv][1] + cc);
    uint32_t u2 = *(const uint32_t*)(base + coff[p][lv][2] + cc);
    uint32_t u3 = *(const uint32_t*)(base + coff[p][lv][3] + cc);
    float lo = bf2f(u0 & 0xffff) * w0 + bf2f(u1 & 0xffff) * w1 +
               bf2f(u2 & 0xffff) * w2 + bf2f(u3 & 0xffff) * w3;
    float hi = bf2f(u0 >> 16) * w0 + bf2f(u1 >> 16) * w1 +
               bf2f(u2 >> 16) * w2 + bf2f(u3 >> 16) * w3;
    uint32_t pv = (uint32_t)f2bf(lo) | ((uint32_t)f2bf(hi) << 16);
    *(uint32_t*)(xt + p * 808 + lv * 192 + cc) = pv;
  }
  __syncthreads();

  // ---- MFMA: each wave: 2 M-tiles x 3 N-tiles
  const int wv = t >> 6, lid = t & 63;
  const int quad = lid >> 4, mrow = lid & 15;
  const int nt0 = wv * 3;

  f32x4 accS[2][3], accP[2][3];
#pragma unroll
  for (int mt = 0; mt < 2; ++mt)
#pragma unroll
    for (int j = 0; j < 3; ++j) { accS[mt][j] = (f32x4)0.0f; accP[mt][j] = (f32x4)0.0f; }

  s16x8 a_last[2];
#pragma unroll 1
  for (int kc = 0; kc < 25; ++kc) {
    int ko = kc * 32 + quad * 8;
    s16x8 a0 = *(const s16x8*)(xt + mrow * 808 + ko);
    s16x8 a1 = *(const s16x8*)(xt + (16 + mrow) * 808 + ko);
#pragma unroll
    for (int j = 0; j < 3; ++j) {
      int n = (nt0 + j) * 16 + mrow;
      s16x8 bw = *(const s16x8*)(Wseed + n * 800 + ko);
      accS[0][j] = __builtin_amdgcn_mfma_f32_16x16x32_bf16(a0, bw, accS[0][j], 0, 0, 0);
      accS[1][j] = __builtin_amdgcn_mfma_f32_16x16x32_bf16(a1, bw, accS[1][j], 0, 0, 0);
    }
    if (kc == 24) { a_last[0] = a0; a_last[1] = a1; }
  }
#pragma unroll
  for (int j = 0; j < 3; ++j) {          // pos: K=32 = PE chunk (cols 768..799)
    int n = (nt0 + j) * 16 + mrow;
    s16x8 bw = *(const s16x8*)(Wpos + n * 32 + quad * 8);
    accP[0][j] = __builtin_amdgcn_mfma_f32_16x16x32_bf16(a_last[0], bw, accP[0][j], 0, 0, 0);
    accP[1][j] = __builtin_amdgcn_mfma_f32_16x16x32_bf16(a_last[1], bw, accP[1][j], 0, 0, 0);
  }

  // ---- pos write (C/D: col=lane&15, row=quad*4+reg)
#pragma unroll
  for (int j = 0; j < 3; ++j) {
    int n = (nt0 + j) * 16 + mrow;
    float pb = pos_b[n];
#pragma unroll
    for (int mt = 0; mt < 2; ++mt)
#pragma unroll
      for (int r = 0; r < 4; ++r) {
        int row = gp0 + mt * 16 + quad * 4 + r;
        out_pos[(size_t)row * 192 + n] = accP[mt][j][r] + pb;
      }
  }

  __syncthreads();                       // all xt reads done; alias as preLN
  float* preLN = (float*)xt;             // [32][193]
#pragma unroll
  for (int j = 0; j < 3; ++j) {
    int n = (nt0 + j) * 16 + mrow;
    float sb = seed_b[n];
#pragma unroll
    for (int mt = 0; mt < 2; ++mt)
#pragma unroll
      for (int r = 0; r < 4; ++r)
        preLN[(mt * 16 + quad * 4 + r) * 193 + n] = accS[mt][j][r] + sb;
  }
  __syncthreads();

  // ---- LayerNorm stats: 8 threads per row
  {
    int r = t >> 3, g = t & 7;
    float s = 0.0f, sq = 0.0f;
    for (int i = 0; i < 24; ++i) {
      float v = preLN[r * 193 + g * 24 + i];
      s += v; sq += v * v;
    }
    for (int d = 4; d > 0; d >>= 1) {
      s += __shfl_down(s, d, 8);
      sq += __shfl_down(sq, d, 8);
    }
    if (g == 0) {
      float mu = s * (1.0f / 192.0f);
      float var = sq * (1.0f / 192.0f) - mu * mu;
      mu_s[r] = mu;
      rs_s[r] = 1.0f / sqrtf(var + 1e-5f);
    }
  }
  __syncthreads();

  // ---- normalized seed write, coalesced
  for (int i = 0; i < 24; ++i) {
    int e = i * 256 + t;
    int r = e / 192, n = e - r * 192;
    float v = (preLN[r * 193 + n] - mu_s[r]) * rs_s[r] * ln_g[n] + ln_b[n];
    out_seed[(size_t)(gp0 + r) * 192 + n] = v;
  }
}

extern "C" void kernel_launch(void* const* d_in, const int* in_sizes, int n_in,
                              void* d_out, int out_size, void* d_ws, size_t ws_size,
                              hipStream_t stream) {
  const float* coords  = (const float*)d_in[0];
  const float* L1      = (const float*)d_in[1];
  const float* L2      = (const float*)d_in[2];
  const float* L3      = (const float*)d_in[3];
  const float* L4      = (const float*)d_in[4];
  const float* Wseed_w = (const float*)d_in[5];
  const float* Wseed_b = (const float*)d_in[6];
  const float* ln_g    = (const float*)d_in[7];
  const float* ln_b    = (const float*)d_in[8];
  const float* Wpos_w  = (const float*)d_in[9];
  const float* Wpos_b  = (const float*)d_in[10];

  u16* T1  = (u16*)d_ws;
  u16* T2  = T1 + (size_t)8 * 16384 * 192;
  u16* T3  = T2 + (size_t)8 * 4096 * 192;
  u16* T4  = T3 + (size_t)8 * 1024 * 192;
  u16* Wsd = T4 + (size_t)8 * 256 * 192;
  u16* Wps = Wsd + 153600;
  // total ws use: ~67.2 MB

  convert_w_kernel<<<600, 256, 0, stream>>>(Wseed_w, Wpos_w, Wsd, Wps);
  transpose_kernel<<<dim3(256, 8), 256, 0, stream>>>(L1, T1, 16384);
  transpose_kernel<<<dim3(64, 8),  256, 0, stream>>>(L2, T2, 4096);
  transpose_kernel<<<dim3(16, 8),  256, 0, stream>>>(L3, T3, 1024);
  transpose_kernel<<<dim3(4, 8),   256, 0, stream>>>(L4, T4, 256);

  float* out_seed = (float*)d_out;
  float* out_pos  = out_seed + (size_t)32768 * 192;
  float* out_cg   = out_pos  + (size_t)32768 * 192;

  seed_main<<<1024, 256, 0, stream>>>(coords, T1, T2, T3, T4, Wsd, Wps,
                                      Wseed_b, ln_g, ln_b, Wpos_b,
                                      out_seed, out_pos, out_cg);
}

// Round 2
// 278.029 us; speedup vs baseline: 1.1059x; 1.1059x over previous
//
#include <hip/hip_runtime.h>
#include <stdint.h>

typedef unsigned short u16;
typedef short s16x8 __attribute__((ext_vector_type(8)));
typedef float f32x4 __attribute__((ext_vector_type(4)));
typedef uint32_t u32x4 __attribute__((ext_vector_type(4)));

__device__ __forceinline__ u16 f2bf(float f) {
  union { float f; uint32_t u; } a; a.f = f;
  uint32_t u = a.u;
  uint32_t r = (u + 0x7fffu + ((u >> 16) & 1u)) >> 16;
  return (u16)r;
}
__device__ __forceinline__ float bf2f(uint32_t hbits) {
  union { uint32_t u; float f; } a; a.u = hbits << 16;
  return a.f;
}

// ---------------------------------------------------------------- fused prep
// blocks [0,2048): L1 transpose; [2048,2560): L2; [2560,2688): L3;
// [2688,2720): L4; [2720,2752): W convert (grid-stride).
// Transpose: [B,192,HW] f32 -> [B,HW,192] bf16, 64-hw x 192-c tile per block.
// LDS tile is channel-pair-packed dwords [96][65] (stride 65 -> <=2-way banks).
__global__ __launch_bounds__(256) void prep_all(
    const float* __restrict__ L1, const float* __restrict__ L2,
    const float* __restrict__ L3, const float* __restrict__ L4,
    const float* __restrict__ ws_w, const float* __restrict__ wp_w,
    u16* __restrict__ T1, u16* __restrict__ T2,
    u16* __restrict__ T3, u16* __restrict__ T4,
    u16* __restrict__ dWs, u16* __restrict__ dWp) {
  const int bid = blockIdx.x;
  const int t = threadIdx.x;

  if (bid >= 2720) {  // ---- W convert: 159744 f32 total as 39936 float4s
    int t0 = (bid - 2720) * 256 + t;
    for (int i = t0; i < 39936; i += 8192) {
      const float* s; u16* d; int off;
      if (i < 38400) { s = ws_w; d = dWs; off = 4 * i; }
      else           { s = wp_w; d = dWp; off = 4 * (i - 38400); }
      f32x4 v = *(const f32x4*)(s + off);
      uint2 o;
      o.x = (uint32_t)f2bf(v.x) | ((uint32_t)f2bf(v.y) << 16);
      o.y = (uint32_t)f2bf(v.z) | ((uint32_t)f2bf(v.w) << 16);
      *(uint2*)(d + off) = o;
    }
    return;
  }

  const float* src; u16* dst; int HW, tiles, rel;
  if (bid < 2048)      { src = L1; dst = T1; HW = 16384; tiles = 256; rel = bid; }
  else if (bid < 2560) { src = L2; dst = T2; HW = 4096;  tiles = 64;  rel = bid - 2048; }
  else if (bid < 2688) { src = L3; dst = T3; HW = 1024;  tiles = 16;  rel = bid - 2560; }
  else                 { src = L4; dst = T4; HW = 256;   tiles = 4;   rel = bid - 2688; }
  const int b = rel / tiles, hw0 = (rel % tiles) * 64;

  __shared__ uint32_t tileD[96 * 65];
  const float* sb = src + (size_t)b * 192 * HW + hw0;
  for (int i = 0; i < 6; ++i) {
    int idx = i * 256 + t;                 // 1536 = 96 c2 x 16 hw4
    int c2 = idx >> 4, hw4 = idx & 15;     // lanes: consecutive hw4 -> coalesced float4
    f32x4 a = *(const f32x4*)(sb + (size_t)(2 * c2) * HW + hw4 * 4);
    f32x4 c = *(const f32x4*)(sb + (size_t)(2 * c2 + 1) * HW + hw4 * 4);
    uint32_t* w = &tileD[c2 * 65 + hw4 * 4];
    w[0] = (uint32_t)f2bf(a.x) | ((uint32_t)f2bf(c.x) << 16);
    w[1] = (uint32_t)f2bf(a.y) | ((uint32_t)f2bf(c.y) << 16);
    w[2] = (uint32_t)f2bf(a.z) | ((uint32_t)f2bf(c.z) << 16);
    w[3] = (uint32_t)f2bf(a.w) | ((uint32_t)f2bf(c.w) << 16);
  }
  __syncthreads();
  uint32_t* d = (uint32_t*)(dst + ((size_t)b * HW + hw0) * 192);
  for (int i = 0; i < 24; ++i) {
    int e = i * 256 + t;                   // 6144 = 64 hw x 96 c2
    int hw = e / 96, c2 = e - hw * 96;     // lanes: consecutive c2 -> coalesced store
    d[hw * 96 + c2] = tileD[c2 * 65 + hw]; // banks (c2*65+hw)%32 -> 2-way (free)
  }
}

// ---------------------------------------------------------------- main fused
// 16 points/block, 2048 blocks, 256 threads (4 waves). xt [16][808] bf16 in
// LDS (25.9 KB -> 5 blocks/CU). Corner math inline in gather (no coff/cw LDS).
__global__ __launch_bounds__(256, 5) void seed_main(
    const float* __restrict__ coords,
    const u16* __restrict__ T1, const u16* __restrict__ T2,
    const u16* __restrict__ T3, const u16* __restrict__ T4,
    const u16* __restrict__ Wseed, const u16* __restrict__ Wpos,
    const float* __restrict__ seed_b, const float* __restrict__ ln_g,
    const float* __restrict__ ln_b, const float* __restrict__ pos_b,
    float* __restrict__ out_seed, float* __restrict__ out_pos,
    float* __restrict__ out_cg) {

  __shared__ __align__(16) u16 xt[16 * 808];   // aliased later as preLN f32 [16][193]
  __shared__ float mu_s[16], rs_s[16];

  const int t = threadIdx.x;
  const int gp0 = blockIdx.x * 16;
  const int b = gp0 >> 12;

  // ---- center grid out
  if (t < 32) {
    int p = t >> 1, xy = t & 1;
    float c = coords[(gp0 + p) * 2 + xy];
    out_cg[(gp0 + p) * 2 + xy] = c * (2.0f / 511.0f) - 1.0f;
  }
  // ---- PE: 16 pts x 32 vals -> xt cols 768..799
  for (int i = 0; i < 2; ++i) {
    int e = i * 256 + t;
    int p = e >> 5, j = e & 31;
    float c = coords[(gp0 + p) * 2 + ((j >> 4) & 1)] * (1.0f / 512.0f);
    float v = c * (float)(1 << (j & 7));
    float a = (v - floorf(v)) * 6.283185307179586f;
    float r = (j & 8) ? __cosf(a) : __sinf(a);
    xt[p * 808 + 768 + j] = f2bf(r);
  }

  // ---- gather: 16 pts x 4 lv x 24 c4-groups (8 ch / 16 B per thread-iter)
  const u16* B1 = T1 + (size_t)b * 16384 * 192;
  const u16* B2 = T2 + (size_t)b * 4096 * 192;
  const u16* B3 = T3 + (size_t)b * 1024 * 192;
  const u16* B4 = T4 + (size_t)b * 256 * 192;
  for (int i = 0; i < 6; ++i) {
    int e = i * 256 + t;               // 1536; lanes: consecutive c4 -> coalesced
    int c4 = e % 24;
    int plv = e / 24;
    int lv = plv & 3, p = plv >> 2;
    float cx = coords[(gp0 + p) * 2 + 0];
    float cy = coords[(gp0 + p) * 2 + 1];
    float gx = cx * (2.0f / 511.0f) - 1.0f;
    float gy = cy * (2.0f / 511.0f) - 1.0f;
    int Wl = 128 >> lv;
    float ix = (gx + 1.0f) * 0.5f * (float)(Wl - 1);
    float iy = (gy + 1.0f) * 0.5f * (float)(Wl - 1);
    float fx = floorf(ix), fy = floorf(iy);
    float wx = ix - fx, wy = iy - fy;
    int x0 = (int)fx, y0 = (int)fy;
    int x1 = min(max(x0 + 1, 0), Wl - 1), y1 = min(max(y0 + 1, 0), Wl - 1);
    x0 = min(max(x0, 0), Wl - 1); y0 = min(max(y0, 0), Wl - 1);
    const u16* base = (lv == 0) ? B1 : (lv == 1) ? B2 : (lv == 2) ? B3 : B4;
    int cc = c4 * 8;
    u32x4 q00 = *(const u32x4*)(base + (y0 * Wl + x0) * 192 + cc);
    u32x4 q01 = *(const u32x4*)(base + (y0 * Wl + x1) * 192 + cc);
    u32x4 q10 = *(const u32x4*)(base + (y1 * Wl + x0) * 192 + cc);
    u32x4 q11 = *(const u32x4*)(base + (y1 * Wl + x1) * 192 + cc);
    float w00 = (1.0f - wx) * (1.0f - wy), w01 = wx * (1.0f - wy);
    float w10 = (1.0f - wx) * wy,          w11 = wx * wy;
    u32x4 o;
#pragma unroll
    for (int k = 0; k < 4; ++k) {
      float lo = bf2f(q00[k] & 0xffff) * w00 + bf2f(q01[k] & 0xffff) * w01 +
                 bf2f(q10[k] & 0xffff) * w10 + bf2f(q11[k] & 0xffff) * w11;
      float hi = bf2f(q00[k] >> 16) * w00 + bf2f(q01[k] >> 16) * w01 +
                 bf2f(q10[k] >> 16) * w10 + bf2f(q11[k] >> 16) * w11;
      o[k] = (uint32_t)f2bf(lo) | ((uint32_t)f2bf(hi) << 16);
    }
    *(u32x4*)(xt + p * 808 + lv * 192 + cc) = o;
  }
  __syncthreads();

  // ---- MFMA: each wave: 1 M-tile(16) x 3 N-tiles
  const int lid = t & 63, wv = t >> 6;
  const int quad = lid >> 4, mrow = lid & 15;
  const int nt0 = wv * 3;

  f32x4 accS[3], accP[3];
#pragma unroll
  for (int j = 0; j < 3; ++j) { accS[j] = (f32x4)0.0f; accP[j] = (f32x4)0.0f; }

  s16x8 a_last;
#pragma unroll 1
  for (int kc = 0; kc < 25; ++kc) {
    int ko = kc * 32 + quad * 8;
    s16x8 a = *(const s16x8*)(xt + mrow * 808 + ko);
#pragma unroll
    for (int j = 0; j < 3; ++j) {
      int n = (nt0 + j) * 16 + mrow;
      s16x8 bw = *(const s16x8*)(Wseed + n * 800 + ko);
      accS[j] = __builtin_amdgcn_mfma_f32_16x16x32_bf16(a, bw, accS[j], 0, 0, 0);
    }
    if (kc == 24) a_last = a;
  }
#pragma unroll
  for (int j = 0; j < 3; ++j) {          // pos: K=32 = PE chunk (cols 768..799)
    int n = (nt0 + j) * 16 + mrow;
    s16x8 bw = *(const s16x8*)(Wpos + n * 32 + quad * 8);
    accP[j] = __builtin_amdgcn_mfma_f32_16x16x32_bf16(a_last, bw, accP[j], 0, 0, 0);
  }

  // ---- pos write (C/D: col=lane&15, row=quad*4+reg)
#pragma unroll
  for (int j = 0; j < 3; ++j) {
    int n = (nt0 + j) * 16 + mrow;
    float pb = pos_b[n];
#pragma unroll
    for (int r = 0; r < 4; ++r)
      out_pos[(size_t)(gp0 + quad * 4 + r) * 192 + n] = accP[j][r] + pb;
  }

  __syncthreads();                       // all xt reads done; alias as preLN
  float* preLN = (float*)xt;             // [16][193]
#pragma unroll
  for (int j = 0; j < 3; ++j) {
    int n = (nt0 + j) * 16 + mrow;
    float sb = seed_b[n];
#pragma unroll
    for (int r = 0; r < 4; ++r)
      preLN[(quad * 4 + r) * 193 + n] = accS[j][r] + sb;
  }
  __syncthreads();

  // ---- LayerNorm stats: 16 threads per row
  {
    int r = t >> 4, g = t & 15;
    float s = 0.0f, sq = 0.0f;
#pragma unroll
    for (int i = 0; i < 12; ++i) {
      float v = preLN[r * 193 + g * 12 + i];
      s += v; sq += v * v;
    }
#pragma unroll
    for (int d = 8; d > 0; d >>= 1) {
      s += __shfl_down(s, d, 16);
      sq += __shfl_down(sq, d, 16);
    }
    if (g == 0) {
      float mu = s * (1.0f / 192.0f);
      float var = sq * (1.0f / 192.0f) - mu * mu;
      mu_s[r] = mu;
      rs_s[r] = 1.0f / sqrtf(var + 1e-5f);
    }
  }
  __syncthreads();

  // ---- normalized seed write, coalesced
  for (int i = 0; i < 12; ++i) {
    int e = i * 256 + t;
    int r = e / 192, n = e - r * 192;
    float v = (preLN[r * 193 + n] - mu_s[r]) * rs_s[r] * ln_g[n] + ln_b[n];
    out_seed[(size_t)(gp0 + r) * 192 + n] = v;
  }
}

extern "C" void kernel_launch(void* const* d_in, const int* in_sizes, int n_in,
                              void* d_out, int out_size, void* d_ws, size_t ws_size,
                              hipStream_t stream) {
  const float* coords  = (const float*)d_in[0];
  const float* L1      = (const float*)d_in[1];
  const float* L2      = (const float*)d_in[2];
  const float* L3      = (const float*)d_in[3];
  const float* L4      = (const float*)d_in[4];
  const float* Wseed_w = (const float*)d_in[5];
  const float* Wseed_b = (const float*)d_in[6];
  const float* ln_g    = (const float*)d_in[7];
  const float* ln_b    = (const float*)d_in[8];
  const float* Wpos_w  = (const float*)d_in[9];
  const float* Wpos_b  = (const float*)d_in[10];

  u16* T1  = (u16*)d_ws;
  u16* T2  = T1 + (size_t)8 * 16384 * 192;
  u16* T3  = T2 + (size_t)8 * 4096 * 192;
  u16* T4  = T3 + (size_t)8 * 1024 * 192;
  u16* Wsd = T4 + (size_t)8 * 256 * 192;
  u16* Wps = Wsd + 153600;

  prep_all<<<2752, 256, 0, stream>>>(L1, L2, L3, L4, Wseed_w, Wpos_w,
                                     T1, T2, T3, T4, Wsd, Wps);

  float* out_seed = (float*)d_out;
  float* out_pos  = out_seed + (size_t)32768 * 192;
  float* out_cg   = out_pos  + (size_t)32768 * 192;

  seed_main<<<2048, 256, 0, stream>>>(coords, T1, T2, T3, T4, Wsd, Wps,
                                      Wseed_b, ln_g, ln_b, Wpos_b,
                                      out_seed, out_pos, out_cg);
}

// Round 3
// 273.890 us; speedup vs baseline: 1.1226x; 1.0151x over previous
//
#include <hip/hip_runtime.h>
#include <hip/hip_bf16.h>
#include <stdint.h>

typedef unsigned short u16;
typedef short s16x8 __attribute__((ext_vector_type(8)));
typedef float f32x4 __attribute__((ext_vector_type(4)));
typedef uint32_t u32x4 __attribute__((ext_vector_type(4)));

__device__ __forceinline__ uint32_t pack_bf16(float lo, float hi) {
  float2 f; f.x = lo; f.y = hi;
  __hip_bfloat162 h = __float22bfloat162_rn(f);
  union { __hip_bfloat162 h; uint32_t u; } c; c.h = h;
  return c.u;
}
__device__ __forceinline__ u16 f2bf(float f) {
  union { float f; uint32_t u; } a; a.f = f;
  uint32_t u = a.u;
  return (u16)((u + 0x7fffu + ((u >> 16) & 1u)) >> 16);
}
__device__ __forceinline__ float bf2f(uint32_t hbits) {
  union { uint32_t u; float f; } a; a.u = hbits << 16;
  return a.f;
}

// ---------------------------------------------------------------- fused prep
// blocks [0,2048): L1 transpose; [2048,2560): L2; [2560,2688): L3;
// [2688,2720): L4; [2720,2752): W convert (grid-stride).
__global__ __launch_bounds__(256) void prep_all(
    const float* __restrict__ L1, const float* __restrict__ L2,
    const float* __restrict__ L3, const float* __restrict__ L4,
    const float* __restrict__ ws_w, const float* __restrict__ wp_w,
    u16* __restrict__ T1, u16* __restrict__ T2,
    u16* __restrict__ T3, u16* __restrict__ T4,
    u16* __restrict__ dWs, u16* __restrict__ dWp) {
  const int bid = blockIdx.x;
  const int t = threadIdx.x;

  if (bid >= 2720) {  // ---- W convert: 159744 f32 total as 39936 float4s
    int t0 = (bid - 2720) * 256 + t;
    for (int i = t0; i < 39936; i += 8192) {
      const float* s; u16* d; int off;
      if (i < 38400) { s = ws_w; d = dWs; off = 4 * i; }
      else           { s = wp_w; d = dWp; off = 4 * (i - 38400); }
      f32x4 v = *(const f32x4*)(s + off);
      uint2 o;
      o.x = pack_bf16(v.x, v.y);
      o.y = pack_bf16(v.z, v.w);
      *(uint2*)(d + off) = o;
    }
    return;
  }

  const float* src; u16* dst; int HW, tiles, rel;
  if (bid < 2048)      { src = L1; dst = T1; HW = 16384; tiles = 256; rel = bid; }
  else if (bid < 2560) { src = L2; dst = T2; HW = 4096;  tiles = 64;  rel = bid - 2048; }
  else if (bid < 2688) { src = L3; dst = T3; HW = 1024;  tiles = 16;  rel = bid - 2560; }
  else                 { src = L4; dst = T4; HW = 256;   tiles = 4;   rel = bid - 2688; }
  const int b = rel / tiles, hw0 = (rel % tiles) * 64;

  __shared__ uint32_t tileD[96 * 65];   // [c2][hw], stride 65 -> <=2-way banks
  const float* sb = src + (size_t)b * 192 * HW + hw0;
  for (int i = 0; i < 6; ++i) {
    int idx = i * 256 + t;                 // 1536 = 96 c2 x 16 hw4
    int c2 = idx >> 4, hw4 = idx & 15;     // lanes: consecutive hw4 -> coalesced float4
    f32x4 a = *(const f32x4*)(sb + (size_t)(2 * c2) * HW + hw4 * 4);
    f32x4 c = *(const f32x4*)(sb + (size_t)(2 * c2 + 1) * HW + hw4 * 4);
    uint32_t* w = &tileD[c2 * 65 + hw4 * 4];
    w[0] = pack_bf16(a.x, c.x);
    w[1] = pack_bf16(a.y, c.y);
    w[2] = pack_bf16(a.z, c.z);
    w[3] = pack_bf16(a.w, c.w);
  }
  __syncthreads();
  uint32_t* d = (uint32_t*)(dst + ((size_t)b * HW + hw0) * 192);
  for (int i = 0; i < 12; ++i) {
    int e = i * 256 + t;                   // 3072 = 64 hw x 48 cp
    int hw = e / 48, cp = e - hw * 48;     // lanes: consecutive cp -> coalesced uint2
    uint2 v;
    v.x = tileD[(cp * 2) * 65 + hw];
    v.y = tileD[(cp * 2 + 1) * 65 + hw];
    *(uint2*)(d + hw * 96 + cp * 2) = v;
  }
}

// ---------------------------------------------------------------- main fused
// 16 points/block, 2048 blocks, 256 threads (4 waves). xt [16][808] bf16 in
// LDS (25.9 KB). Gather: one (point,level) per thread, 6 channel chunks.
__global__ __launch_bounds__(256, 4) void seed_main(
    const float* __restrict__ coords,
    const u16* __restrict__ T1, const u16* __restrict__ T2,
    const u16* __restrict__ T3, const u16* __restrict__ T4,
    const u16* __restrict__ Wseed, const u16* __restrict__ Wpos,
    const float* __restrict__ seed_b, const float* __restrict__ ln_g,
    const float* __restrict__ ln_b, const float* __restrict__ pos_b,
    float* __restrict__ out_seed, float* __restrict__ out_pos,
    float* __restrict__ out_cg) {

  __shared__ __align__(16) u16 xt[16 * 808];   // aliased later as preLN f32 [16][193]
  __shared__ float mu_s[16], rs_s[16];

  const int t = threadIdx.x;
  const int gp0 = blockIdx.x * 16;
  const int b = gp0 >> 12;

  // ---- center grid out
  if (t < 32) {
    int p = t >> 1, xy = t & 1;
    float c = coords[(gp0 + p) * 2 + xy];
    out_cg[(gp0 + p) * 2 + xy] = c * (2.0f / 511.0f) - 1.0f;
  }
  // ---- PE: 16 pts x 32 vals -> xt cols 768..799
  for (int i = 0; i < 2; ++i) {
    int e = i * 256 + t;
    int p = e >> 5, j = e & 31;
    float c = coords[(gp0 + p) * 2 + ((j >> 4) & 1)] * (1.0f / 512.0f);
    float v = c * (float)(1 << (j & 7));
    float a = (v - floorf(v)) * 6.283185307179586f;
    float r = (j & 8) ? __cosf(a) : __sinf(a);
    xt[p * 808 + 768 + j] = f2bf(r);
  }

  // ---- gather: thread owns one (p,lv); 6 chunks of 8 channels (16 B loads)
  {
    const u16* B1 = T1 + (size_t)b * 16384 * 192;
    const u16* B2 = T2 + (size_t)b * 4096 * 192;
    const u16* B3 = T3 + (size_t)b * 1024 * 192;
    const u16* B4 = T4 + (size_t)b * 256 * 192;
    int plv = t >> 2;                  // [0,64)
    int lv = plv & 3, p = plv >> 2;
    int c4b = t & 3;                   // chunk phase
    float cx = coords[(gp0 + p) * 2 + 0];
    float cy = coords[(gp0 + p) * 2 + 1];
    float gx = cx * (2.0f / 511.0f) - 1.0f;
    float gy = cy * (2.0f / 511.0f) - 1.0f;
    int Wl = 128 >> lv;
    float ix = (gx + 1.0f) * 0.5f * (float)(Wl - 1);
    float iy = (gy + 1.0f) * 0.5f * (float)(Wl - 1);
    float fx = floorf(ix), fy = floorf(iy);
    float wx = ix - fx, wy = iy - fy;
    int x0 = (int)fx, y0 = (int)fy;
    int x1 = min(max(x0 + 1, 0), Wl - 1), y1 = min(max(y0 + 1, 0), Wl - 1);
    x0 = min(max(x0, 0), Wl - 1); y0 = min(max(y0, 0), Wl - 1);
    const u16* base = (lv == 0) ? B1 : (lv == 1) ? B2 : (lv == 2) ? B3 : B4;
    const u16* b00 = base + (y0 * Wl + x0) * 192;
    const u16* b01 = base + (y0 * Wl + x1) * 192;
    const u16* b10 = base + (y1 * Wl + x0) * 192;
    const u16* b11 = base + (y1 * Wl + x1) * 192;
    float w00 = (1.0f - wx) * (1.0f - wy), w01 = wx * (1.0f - wy);
    float w10 = (1.0f - wx) * wy,          w11 = wx * wy;
    u16* dstp = xt + p * 808 + lv * 192;
#pragma unroll
    for (int i = 0; i < 6; ++i) {
      int cc = (c4b + 4 * i) * 8;
      u32x4 q00 = *(const u32x4*)(b00 + cc);
      u32x4 q01 = *(const u32x4*)(b01 + cc);
      u32x4 q10 = *(const u32x4*)(b10 + cc);
      u32x4 q11 = *(const u32x4*)(b11 + cc);
      u32x4 o;
#pragma unroll
      for (int k = 0; k < 4; ++k) {
        float lo = bf2f(q00[k] & 0xffff) * w00 + bf2f(q01[k] & 0xffff) * w01 +
                   bf2f(q10[k] & 0xffff) * w10 + bf2f(q11[k] & 0xffff) * w11;
        float hi = bf2f(q00[k] >> 16) * w00 + bf2f(q01[k] >> 16) * w01 +
                   bf2f(q10[k] >> 16) * w10 + bf2f(q11[k] >> 16) * w11;
        o[k] = pack_bf16(lo, hi);
      }
      *(u32x4*)(dstp + cc) = o;
    }
  }
  __syncthreads();

  // ---- MFMA: each wave: 1 M-tile(16) x 3 N-tiles, pipelined K-loop
  const int lid = t & 63, wv = t >> 6;
  const int quad = lid >> 4, mrow = lid & 15;
  const int nt0 = wv * 3;

  f32x4 accS[3], accP[3];
#pragma unroll
  for (int j = 0; j < 3; ++j) { accS[j] = (f32x4)0.0f; accP[j] = (f32x4)0.0f; }

  const u16* wp0 = Wseed + (size_t)((nt0 + 0) * 16 + mrow) * 800 + quad * 8;
  const u16* wp1 = wp0 + 16 * 800;
  const u16* wp2 = wp1 + 16 * 800;
  const u16* arow = xt + mrow * 808 + quad * 8;

  s16x8 a_last;
#pragma unroll 5
  for (int kc = 0; kc < 25; ++kc) {
    int ko = kc * 32;
    s16x8 a = *(const s16x8*)(arow + ko);
    s16x8 b0 = *(const s16x8*)(wp0 + ko);
    s16x8 b1 = *(const s16x8*)(wp1 + ko);
    s16x8 b2 = *(const s16x8*)(wp2 + ko);
    accS[0] = __builtin_amdgcn_mfma_f32_16x16x32_bf16(a, b0, accS[0], 0, 0, 0);
    accS[1] = __builtin_amdgcn_mfma_f32_16x16x32_bf16(a, b1, accS[1], 0, 0, 0);
    accS[2] = __builtin_amdgcn_mfma_f32_16x16x32_bf16(a, b2, accS[2], 0, 0, 0);
    if (kc == 24) a_last = a;
  }
#pragma unroll
  for (int j = 0; j < 3; ++j) {          // pos: K=32 = PE chunk (cols 768..799)
    int n = (nt0 + j) * 16 + mrow;
    s16x8 bw = *(const s16x8*)(Wpos + n * 32 + quad * 8);
    accP[j] = __builtin_amdgcn_mfma_f32_16x16x32_bf16(a_last, bw, accP[j], 0, 0, 0);
  }

  // ---- pos write (C/D: col=lane&15, row=quad*4+reg)
#pragma unroll
  for (int j = 0; j < 3; ++j) {
    int n = (nt0 + j) * 16 + mrow;
    float pb = pos_b[n];
#pragma unroll
    for (int r = 0; r < 4; ++r)
      out_pos[(size_t)(gp0 + quad * 4 + r) * 192 + n] = accP[j][r] + pb;
  }

  __syncthreads();                       // all xt reads done; alias as preLN
  float* preLN = (float*)xt;             // [16][193]
#pragma unroll
  for (int j = 0; j < 3; ++j) {
    int n = (nt0 + j) * 16 + mrow;
    float sb = seed_b[n];
#pragma unroll
    for (int r = 0; r < 4; ++r)
      preLN[(quad * 4 + r) * 193 + n] = accS[j][r] + sb;
  }
  __syncthreads();

  // ---- LayerNorm stats: 16 threads per row
  {
    int r = t >> 4, g = t & 15;
    float s = 0.0f, sq = 0.0f;
#pragma unroll
    for (int i = 0; i < 12; ++i) {
      float v = preLN[r * 193 + g * 12 + i];
      s += v; sq += v * v;
    }
#pragma unroll
    for (int d = 8; d > 0; d >>= 1) {
      s += __shfl_down(s, d, 16);
      sq += __shfl_down(sq, d, 16);
    }
    if (g == 0) {
      float mu = s * (1.0f / 192.0f);
      float var = sq * (1.0f / 192.0f) - mu * mu;
      mu_s[r] = mu;
      rs_s[r] = 1.0f / sqrtf(var + 1e-5f);
    }
  }
  __syncthreads();

  // ---- normalized seed write, coalesced
  for (int i = 0; i < 12; ++i) {
    int e = i * 256 + t;
    int r = e / 192, n = e - r * 192;
    float v = (preLN[r * 193 + n] - mu_s[r]) * rs_s[r] * ln_g[n] + ln_b[n];
    out_seed[(size_t)(gp0 + r) * 192 + n] = v;
  }
}

extern "C" void kernel_launch(void* const* d_in, const int* in_sizes, int n_in,
                              void* d_out, int out_size, void* d_ws, size_t ws_size,
                              hipStream_t stream) {
  const float* coords  = (const float*)d_in[0];
  const float* L1      = (const float*)d_in[1];
  const float* L2      = (const float*)d_in[2];
  const float* L3      = (const float*)d_in[3];
  const float* L4      = (const float*)d_in[4];
  const float* Wseed_w = (const float*)d_in[5];
  const float* Wseed_b = (const float*)d_in[6];
  const float* ln_g    = (const float*)d_in[7];
  const float* ln_b    = (const float*)d_in[8];
  const float* Wpos_w  = (const float*)d_in[9];
  const float* Wpos_b  = (const float*)d_in[10];

  u16* T1  = (u16*)d_ws;
  u16* T2  = T1 + (size_t)8 * 16384 * 192;
  u16* T3  = T2 + (size_t)8 * 4096 * 192;
  u16* T4  = T3 + (size_t)8 * 1024 * 192;
  u16* Wsd = T4 + (size_t)8 * 256 * 192;
  u16* Wps = Wsd + 153600;

  prep_all<<<2752, 256, 0, stream>>>(L1, L2, L3, L4, Wseed_w, Wpos_w,
                                     T1, T2, T3, T4, Wsd, Wps);

  float* out_seed = (float*)d_out;
  float* out_pos  = out_seed + (size_t)32768 * 192;
  float* out_cg   = out_pos  + (size_t)32768 * 192;

  seed_main<<<2048, 256, 0, stream>>>(coords, T1, T2, T3, T4, Wsd, Wps,
                                      Wseed_b, ln_g, ln_b, Wpos_b,
                                      out_seed, out_pos, out_cg);
}